// Round 11
// baseline (118.094 us; speedup 1.0000x reference)
//
#include <hip/hip_runtime.h>
#include <hip/hip_bf16.h>
#include <hip/hip_cooperative_groups.h>

namespace cg = cooperative_groups;

#define NN 128
#define CC 1001
#define RR 51
#define KK 10
#define NK (NN*KK)              // 1280
#define BT_ELEMS (NN*KK*NN*KK) // 1,638,400
#define W_BIN_C 1.0f
#define MIX_C 10000.0f

typedef float f4_t __attribute__((ext_vector_type(4)));
typedef f4_t f4u __attribute__((aligned(4)));   // 4-byte-aligned float4 load

// ---------------- top-k: one wave per row, all-register ----------------
__global__ __launch_bounds__(64) void topk_kernel(const float* __restrict__ roi,
                                                  int* __restrict__ labels,
                                                  float* __restrict__ unary) {
    int a = blockIdx.x, lane = threadIdx.x;
    const float* rowp = roi + a * CC;
    float v[16];
    #pragma unroll
    for (int j = 0; j < 16; ++j) {
        int c = lane + 64 * j;
        v[j] = (c < CC) ? rowp[c] : -1e30f;
    }
    for (int k = 0; k < KK; ++k) {
        float bv = v[0]; int bj = 0;
        #pragma unroll
        for (int j = 1; j < 16; ++j) if (v[j] > bv) { bv = v[j]; bj = j; }  // ascending: lowest j on tie
        int bc = lane + 64 * bj;
        #pragma unroll
        for (int m = 32; m > 0; m >>= 1) {
            float v2 = __shfl_xor(bv, m, 64);
            int   c2 = __shfl_xor(bc, m, 64);
            if (v2 > bv || (v2 == bv && c2 < bc)) { bv = v2; bc = c2; }
        }
        if (lane == (bc & 63)) {
            int j = bc >> 6;
            #pragma unroll
            for (int jj = 0; jj < 16; ++jj) if (jj == j) v[jj] = -1e30f;  // static index clear
        }
        if (lane == 0) {
            labels[a * KK + k] = bc;
            unary[a * KK + k]  = logf(bv);
        }
    }
}

// ---------------- fused raw + symmetrize + log ----------------
// XCD-swizzled block mapping: xcd = orig&7, idx = orig>>3,
// a = (idx>>7)*8 + xcd, b = idx&127. Under round-robin block->XCD dispatch,
// XCD c processes a = c, 8+c, ... sequentially, each a's full b-sweep staying
// on that XCD -> the ~3MB used-row set of relmat[La_k,*]/[*,La_k] is
// L2-resident across the sweep. [R10: 95 -> 79.8 us total]
// 8-lane group per (k,l): lanes 0..5 two f4 (r0..47), lane 6 f4 at r=47 with
// x-coeff zeroed; both directional dots summed before one 3-step reduce.
__global__ __launch_bounds__(256) void pair_kernel(const float* __restrict__ rel_scores,
                                                   const float* __restrict__ relmat,
                                                   const int* __restrict__ labels,
                                                   float* __restrict__ bt) {
    int orig = blockIdx.x;
    int xcd = orig & 7;
    int idx = orig >> 3;
    int a = (idx >> 7) * 8 + xcd;
    int b = idx & 127;
    if (a > b) return;
    int t = threadIdx.x;
    if (a == b) {
        if (t < 100) {
            int k = t / 10, l = t % 10;
            bt[((a * KK + k) * NN + a) * KK + l] = 0.0f;
        }
        return;
    }

    __shared__ int   La[KK], Lb[KK];
    __shared__ int   baseAB[100], baseBA[100], oAB[100], oBA[100];
    __shared__ float eAB[RR], eBA[RR];

    if (t < KK)            La[t]      = labels[a * KK + t];
    else if (t < 2 * KK)   Lb[t - KK] = labels[b * KK + (t - KK)];
    if (t >= 64  && t < 64 + RR)  eAB[t - 64]  = expf(rel_scores[(a * NN + b) * RR + (t - 64)]);
    if (t >= 128 && t < 128 + RR) eBA[t - 128] = expf(rel_scores[(b * NN + a) * RR + (t - 128)]);
    __syncthreads();
    if (t < 100) {
        int k = t / 10, l = t % 10;
        baseAB[t] = (La[k] * CC + Lb[l]) * RR;
        baseBA[t] = (Lb[l] * CC + La[k]) * RR;
        oAB[t]    = ((a * KK + k) * NN + b) * KK + l;
        oBA[t]    = ((b * KK + l) * NN + a) * KK + k;
    }
    __syncthreads();

    int gid = t >> 3;      // 0..31
    int sub = t & 7;
    bool act0 = sub < 7, act1 = sub < 6;
    int r0 = (sub < 6) ? sub * 8 : 47;   // lane 6: r=47..50, x zeroed (47 counted by lane 5)
    int r1 = sub * 8 + 4;

    f4_t zero; zero.x = zero.y = zero.z = zero.w = 0.f;
    f4_t c0A = zero, c1A = zero, c0B = zero, c1B = zero;
    if (sub < 6) {
        c0A.x = eAB[r0];   c0A.y = eAB[r0+1]; c0A.z = eAB[r0+2]; c0A.w = eAB[r0+3];
        c1A.x = eAB[r1];   c1A.y = eAB[r1+1]; c1A.z = eAB[r1+2]; c1A.w = eAB[r1+3];
        c0B.x = eBA[r0];   c0B.y = eBA[r0+1]; c0B.z = eBA[r0+2]; c0B.w = eBA[r0+3];
        c1B.x = eBA[r1];   c1B.y = eBA[r1+1]; c1B.z = eBA[r1+2]; c1B.w = eBA[r1+3];
    } else if (sub == 6) {
        c0A.x = 0.f; c0A.y = eAB[48]; c0A.z = eAB[49]; c0A.w = eAB[50];
        c0B.x = 0.f; c0B.y = eBA[48]; c0B.z = eBA[49]; c0B.w = eBA[50];
    }

    f4_t A0[4], A1[4], B0[4], B1[4];
    #pragma unroll
    for (int u = 0; u < 4; ++u) {
        int kl = gid + 32 * u;
        bool h = (kl < 100);
        int kls = h ? kl : 0;
        int bA = baseAB[kls], bB = baseBA[kls];
        A0[u] = (h && act0) ? *(const f4u*)(relmat + bA + r0) : zero;
        A1[u] = (h && act1) ? *(const f4u*)(relmat + bA + r1) : zero;
        B0[u] = (h && act0) ? *(const f4u*)(relmat + bB + r0) : zero;
        B1[u] = (h && act1) ? *(const f4u*)(relmat + bB + r1) : zero;
    }
    float s[4];
    #pragma unroll
    for (int u = 0; u < 4; ++u) {
        s[u] = A0[u].x*c0A.x + A0[u].y*c0A.y + A0[u].z*c0A.z + A0[u].w*c0A.w
             + A1[u].x*c1A.x + A1[u].y*c1A.y + A1[u].z*c1A.z + A1[u].w*c1A.w
             + B0[u].x*c0B.x + B0[u].y*c0B.y + B0[u].z*c0B.z + B0[u].w*c0B.w
             + B1[u].x*c1B.x + B1[u].y*c1B.y + B1[u].z*c1B.z + B1[u].w*c1B.w;
    }
    #pragma unroll
    for (int m = 4; m > 0; m >>= 1) {
        #pragma unroll
        for (int u = 0; u < 4; ++u) s[u] += __shfl_xor(s[u], m, 64);
    }
    if (sub == 0) {
        #pragma unroll
        for (int u = 0; u < 4; ++u) {
            int kl = gid + 32 * u;
            if (kl < 100) {
                float vv = logf(0.5f * s[u]);
                bt[oAB[kl]] = vv;
                bt[oBA[kl]] = vv;
            }
        }
    }
}

// ---------------- all 3 mean-field rounds + output, one cooperative kernel ----------------
// 128 blocks x 640 threads (10 waves; wave k owns bt row (a,k)). grid.sync()
// between rounds replaces 2 kernel launches.
__global__ __launch_bounds__(640) void rounds_kernel(const float* __restrict__ bt,
                                                     const float* __restrict__ unary,
                                                     float* __restrict__ QA,
                                                     float* __restrict__ QB,
                                                     const float* __restrict__ roi,
                                                     const int* __restrict__ labels,
                                                     float* __restrict__ out) {
    cg::grid_group grid = cg::this_grid();
    int a = blockIdx.x, t = threadIdx.x;
    int wave = t >> 6, lane = t & 63;
    __shared__ float sQ[NK];
    __shared__ float smsg[KK];
    __shared__ float sq[KK];
    __shared__ int   sL[KK];

    const f4_t* row = (const f4_t*)(bt + (a * KK + wave) * NK);
    float un[KK];   // per-thread copy only used by t==0; load once
    if (t == 0) {
        #pragma unroll
        for (int k = 0; k < KK; ++k) un[k] = unary[a * KK + k];
    }
    if (t >= 320 && t < 320 + KK) sL[t - 320] = labels[a * KK + (t - 320)];

    // ---- round 1: uniform Q = 1/K  ->  msg = rowsum/K ----
    {
        float acc = 0.f;
        #pragma unroll
        for (int j = 0; j < 5; ++j) {
            f4_t r = row[lane + 64 * j];
            acc += r.x + r.y + r.z + r.w;
        }
        acc *= (1.0f / (float)KK);
        #pragma unroll
        for (int m = 32; m > 0; m >>= 1) acc += __shfl_xor(acc, m, 64);
        if (lane == 0) smsg[wave] = acc;
        __syncthreads();
        if (t == 0) {
            float e[KK], mx = -1e30f;
            #pragma unroll
            for (int k = 0; k < KK; ++k) {
                float v = W_BIN_C * smsg[k] + un[k];
                e[k] = v;
                if (v > mx) mx = v;
            }
            float ssum = 0.f;
            #pragma unroll
            for (int k = 0; k < KK; ++k) { e[k] = expf(e[k] - mx); ssum += e[k]; }
            #pragma unroll
            for (int k = 0; k < KK; ++k) QA[a * KK + k] = e[k] / ssum;
        }
    }
    grid.sync();

    // ---- round 2: read QA (all), write QB ----
    {
        if (t < NK / 4) ((f4_t*)sQ)[t] = ((const f4_t*)QA)[t];
        __syncthreads();
        const f4_t* q4 = (const f4_t*)sQ;
        float acc = 0.f;
        #pragma unroll
        for (int j = 0; j < 5; ++j) {
            f4_t r = row[lane + 64 * j];
            f4_t q = q4[lane + 64 * j];
            acc += r.x * q.x + r.y * q.y + r.z * q.z + r.w * q.w;
        }
        #pragma unroll
        for (int m = 32; m > 0; m >>= 1) acc += __shfl_xor(acc, m, 64);
        if (lane == 0) smsg[wave] = acc;
        __syncthreads();
        if (t == 0) {
            float e[KK], mx = -1e30f;
            #pragma unroll
            for (int k = 0; k < KK; ++k) {
                float v = W_BIN_C * smsg[k] + un[k];
                e[k] = v;
                if (v > mx) mx = v;
            }
            float ssum = 0.f;
            #pragma unroll
            for (int k = 0; k < KK; ++k) { e[k] = expf(e[k] - mx); ssum += e[k]; }
            #pragma unroll
            for (int k = 0; k < KK; ++k) QB[a * KK + k] = e[k] / ssum;
        }
    }
    grid.sync();

    // ---- round 3 + output scatter/mix ----
    {
        if (t < NK / 4) ((f4_t*)sQ)[t] = ((const f4_t*)QB)[t];
        __syncthreads();
        const f4_t* q4 = (const f4_t*)sQ;
        float acc = 0.f;
        #pragma unroll
        for (int j = 0; j < 5; ++j) {
            f4_t r = row[lane + 64 * j];
            f4_t q = q4[lane + 64 * j];
            acc += r.x * q.x + r.y * q.y + r.z * q.z + r.w * q.w;
        }
        #pragma unroll
        for (int m = 32; m > 0; m >>= 1) acc += __shfl_xor(acc, m, 64);
        if (lane == 0) smsg[wave] = acc;
        __syncthreads();
        if (t == 0) {
            float e[KK], mx = -1e30f;
            #pragma unroll
            for (int k = 0; k < KK; ++k) {
                float v = W_BIN_C * smsg[k] + un[k];
                e[k] = v;
                if (v > mx) mx = v;
            }
            float ssum = 0.f;
            #pragma unroll
            for (int k = 0; k < KK; ++k) { e[k] = expf(e[k] - mx); ssum += e[k]; }
            #pragma unroll
            for (int k = 0; k < KK; ++k) sq[k] = e[k] / ssum;
        }
        __syncthreads();
        for (int c = t; c < CC; c += 640) {
            float q = 0.f;
            #pragma unroll
            for (int k = 0; k < KK; ++k) if (sL[k] == c) q = sq[k];
            out[a * CC + c] = (roi[a * CC + c] + MIX_C * q) / (1.0f + MIX_C);
        }
    }
}

extern "C" void kernel_launch(void* const* d_in, const int* in_sizes, int n_in,
                              void* d_out, int out_size, void* d_ws, size_t ws_size,
                              hipStream_t stream) {
    const float* roi    = (const float*)d_in[0];  // (128, 1001)
    const float* rel    = (const float*)d_in[1];  // (16384, 51)
    const float* relmat = (const float*)d_in[2];  // (1001, 1001, 51)
    float* out = (float*)d_out;

    // workspace layout (16B-aligned)
    char* ws = (char*)d_ws;
    float* bt     = (float*)ws;                                   // 6,553,600 B
    int*   labels = (int*)(ws + (size_t)BT_ELEMS * 4);            // 5,120 B
    float* unary  = (float*)(ws + (size_t)BT_ELEMS * 4 + 5120);   // 5,120 B
    float* QA     = unary + NK;
    float* QB     = QA + NK;

    topk_kernel<<<NN, 64, 0, stream>>>(roi, labels, unary);
    pair_kernel<<<NN * NN, 256, 0, stream>>>(rel, relmat, labels, bt);

    void* args[] = {(void*)&bt, (void*)&unary, (void*)&QA, (void*)&QB,
                    (void*)&roi, (void*)&labels, (void*)&out};
    hipLaunchCooperativeKernel((void*)rounds_kernel, dim3(NN), dim3(640),
                               args, 0, stream);
}

// Round 12
// 93.038 us; speedup vs baseline: 1.2693x; 1.2693x over previous
//
#include <hip/hip_runtime.h>
#include <hip/hip_bf16.h>

#define NN 128
#define CC 1001
#define RR 51
#define KK 10
#define NK (NN*KK)              // 1280
#define BT_ELEMS (NN*KK*NN*KK) // 1,638,400
#define W_BIN_C 1.0f
#define MIX_C 10000.0f

typedef float f4_t __attribute__((ext_vector_type(4)));
typedef f4_t f4u __attribute__((aligned(4)));   // 4-byte-aligned float4 load

// ---------------- top-k: one wave per row, all-register ----------------
__global__ __launch_bounds__(64) void topk_kernel(const float* __restrict__ roi,
                                                  int* __restrict__ labels,
                                                  float* __restrict__ unary) {
    int a = blockIdx.x, lane = threadIdx.x;
    const float* rowp = roi + a * CC;
    float v[16];
    #pragma unroll
    for (int j = 0; j < 16; ++j) {
        int c = lane + 64 * j;
        v[j] = (c < CC) ? rowp[c] : -1e30f;
    }
    for (int k = 0; k < KK; ++k) {
        float bv = v[0]; int bj = 0;
        #pragma unroll
        for (int j = 1; j < 16; ++j) if (v[j] > bv) { bv = v[j]; bj = j; }  // ascending: lowest j on tie
        int bc = lane + 64 * bj;
        #pragma unroll
        for (int m = 32; m > 0; m >>= 1) {
            float v2 = __shfl_xor(bv, m, 64);
            int   c2 = __shfl_xor(bc, m, 64);
            if (v2 > bv || (v2 == bv && c2 < bc)) { bv = v2; bc = c2; }
        }
        if (lane == (bc & 63)) {
            int j = bc >> 6;
            #pragma unroll
            for (int jj = 0; jj < 16; ++jj) if (jj == j) v[jj] = -1e30f;  // static index clear
        }
        if (lane == 0) {
            labels[a * KK + k] = bc;
            unary[a * KK + k]  = logf(bv);
        }
    }
}

// ---------------- fused raw + symmetrize + log ----------------
// XCD-swizzled block mapping: xcd = orig&7, idx = orig>>3,
// a = (idx>>7)*8 + xcd, b = idx&127. Under round-robin block->XCD dispatch,
// XCD c processes a = c, 8+c, ... sequentially, each a's full b-sweep staying
// on that XCD -> the ~3MB used-row set of relmat[La_k,*]/[*,La_k] is
// L2-resident across the sweep. [R10: 95 -> 79.8 us total]
__global__ __launch_bounds__(256) void pair_kernel(const float* __restrict__ rel_scores,
                                                   const float* __restrict__ relmat,
                                                   const int* __restrict__ labels,
                                                   float* __restrict__ bt) {
    int orig = blockIdx.x;
    int xcd = orig & 7;
    int idx = orig >> 3;
    int a = (idx >> 7) * 8 + xcd;
    int b = idx & 127;
    if (a > b) return;
    int t = threadIdx.x;
    if (a == b) {
        if (t < 100) {
            int k = t / 10, l = t % 10;
            bt[((a * KK + k) * NN + a) * KK + l] = 0.0f;
        }
        return;
    }

    __shared__ int   La[KK], Lb[KK];
    __shared__ int   baseAB[100], baseBA[100], oAB[100], oBA[100];
    __shared__ float eAB[RR], eBA[RR];

    if (t < KK)            La[t]      = labels[a * KK + t];
    else if (t < 2 * KK)   Lb[t - KK] = labels[b * KK + (t - KK)];
    if (t >= 64  && t < 64 + RR)  eAB[t - 64]  = expf(rel_scores[(a * NN + b) * RR + (t - 64)]);
    if (t >= 128 && t < 128 + RR) eBA[t - 128] = expf(rel_scores[(b * NN + a) * RR + (t - 128)]);
    __syncthreads();
    if (t < 100) {
        int k = t / 10, l = t % 10;
        baseAB[t] = (La[k] * CC + Lb[l]) * RR;
        baseBA[t] = (Lb[l] * CC + La[k]) * RR;
        oAB[t]    = ((a * KK + k) * NN + b) * KK + l;
        oBA[t]    = ((b * KK + l) * NN + a) * KK + k;
    }
    __syncthreads();

    int gid = t >> 3;      // 0..31
    int sub = t & 7;
    bool act0 = sub < 7, act1 = sub < 6;
    int r0 = (sub < 6) ? sub * 8 : 47;   // lane 6: r=47..50, x zeroed (47 counted by lane 5)
    int r1 = sub * 8 + 4;

    f4_t zero; zero.x = zero.y = zero.z = zero.w = 0.f;
    f4_t c0A = zero, c1A = zero, c0B = zero, c1B = zero;
    if (sub < 6) {
        c0A.x = eAB[r0];   c0A.y = eAB[r0+1]; c0A.z = eAB[r0+2]; c0A.w = eAB[r0+3];
        c1A.x = eAB[r1];   c1A.y = eAB[r1+1]; c1A.z = eAB[r1+2]; c1A.w = eAB[r1+3];
        c0B.x = eBA[r0];   c0B.y = eBA[r0+1]; c0B.z = eBA[r0+2]; c0B.w = eBA[r0+3];
        c1B.x = eBA[r1];   c1B.y = eBA[r1+1]; c1B.z = eBA[r1+2]; c1B.w = eBA[r1+3];
    } else if (sub == 6) {
        c0A.x = 0.f; c0A.y = eAB[48]; c0A.z = eAB[49]; c0A.w = eAB[50];
        c0B.x = 0.f; c0B.y = eBA[48]; c0B.z = eBA[49]; c0B.w = eBA[50];
    }

    f4_t A0[4], A1[4], B0[4], B1[4];
    #pragma unroll
    for (int u = 0; u < 4; ++u) {
        int kl = gid + 32 * u;
        bool h = (kl < 100);
        int kls = h ? kl : 0;
        int bA = baseAB[kls], bB = baseBA[kls];
        A0[u] = (h && act0) ? *(const f4u*)(relmat + bA + r0) : zero;
        A1[u] = (h && act1) ? *(const f4u*)(relmat + bA + r1) : zero;
        B0[u] = (h && act0) ? *(const f4u*)(relmat + bB + r0) : zero;
        B1[u] = (h && act1) ? *(const f4u*)(relmat + bB + r1) : zero;
    }
    float s[4];
    #pragma unroll
    for (int u = 0; u < 4; ++u) {
        s[u] = A0[u].x*c0A.x + A0[u].y*c0A.y + A0[u].z*c0A.z + A0[u].w*c0A.w
             + A1[u].x*c1A.x + A1[u].y*c1A.y + A1[u].z*c1A.z + A1[u].w*c1A.w
             + B0[u].x*c0B.x + B0[u].y*c0B.y + B0[u].z*c0B.z + B0[u].w*c0B.w
             + B1[u].x*c1B.x + B1[u].y*c1B.y + B1[u].z*c1B.z + B1[u].w*c1B.w;
    }
    #pragma unroll
    for (int m = 4; m > 0; m >>= 1) {
        #pragma unroll
        for (int u = 0; u < 4; ++u) s[u] += __shfl_xor(s[u], m, 64);
    }
    if (sub == 0) {
        #pragma unroll
        for (int u = 0; u < 4; ++u) {
            int kl = gid + 32 * u;
            if (kl < 100) {
                float vv = logf(0.5f * s[u]);
                bt[oAB[kl]] = vv;
                bt[oBA[kl]] = vv;
            }
        }
    }
}

// ---------------- manual grid barrier (128 blocks, all co-resident: 1 block/CU) ----------------
// Release on arrive, acquire on leave (agent scope -> proper wbl2/inv for
// cross-XCD visibility). Counter is memset to 0 before each launch.
__device__ inline void grid_barrier(int* cnt, int target) {
    __syncthreads();
    if (threadIdx.x == 0) {
        __hip_atomic_fetch_add(cnt, 1, __ATOMIC_ACQ_REL, __HIP_MEMORY_SCOPE_AGENT);
        while (__hip_atomic_load(cnt, __ATOMIC_ACQUIRE, __HIP_MEMORY_SCOPE_AGENT) < target) {
            __builtin_amdgcn_s_sleep(1);
        }
    }
    __syncthreads();
}

// ---------------- all 3 mean-field rounds + output, one normal launch ----------------
// 128 blocks x 640 threads (10 waves; wave k owns bt row (a,k)).
__global__ __launch_bounds__(640) void rounds_kernel(const float* __restrict__ bt,
                                                     const float* __restrict__ unary,
                                                     float* __restrict__ QA,
                                                     float* __restrict__ QB,
                                                     const float* __restrict__ roi,
                                                     const int* __restrict__ labels,
                                                     float* __restrict__ out,
                                                     int* __restrict__ sync_cnt) {
    int a = blockIdx.x, t = threadIdx.x;
    int wave = t >> 6, lane = t & 63;
    __shared__ float sQ[NK];
    __shared__ float smsg[KK];
    __shared__ float sq[KK];
    __shared__ int   sL[KK];

    const f4_t* row = (const f4_t*)(bt + (a * KK + wave) * NK);
    float un[KK];   // only used by t==0
    if (t == 0) {
        #pragma unroll
        for (int k = 0; k < KK; ++k) un[k] = unary[a * KK + k];
    }
    if (t >= 320 && t < 320 + KK) sL[t - 320] = labels[a * KK + (t - 320)];

    // ---- round 1: uniform Q = 1/K  ->  msg = rowsum/K ----
    {
        float acc = 0.f;
        #pragma unroll
        for (int j = 0; j < 5; ++j) {
            f4_t r = row[lane + 64 * j];
            acc += r.x + r.y + r.z + r.w;
        }
        acc *= (1.0f / (float)KK);
        #pragma unroll
        for (int m = 32; m > 0; m >>= 1) acc += __shfl_xor(acc, m, 64);
        if (lane == 0) smsg[wave] = acc;
        __syncthreads();
        if (t == 0) {
            float e[KK], mx = -1e30f;
            #pragma unroll
            for (int k = 0; k < KK; ++k) {
                float v = W_BIN_C * smsg[k] + un[k];
                e[k] = v;
                if (v > mx) mx = v;
            }
            float ssum = 0.f;
            #pragma unroll
            for (int k = 0; k < KK; ++k) { e[k] = expf(e[k] - mx); ssum += e[k]; }
            #pragma unroll
            for (int k = 0; k < KK; ++k) QA[a * KK + k] = e[k] / ssum;
        }
    }
    grid_barrier(sync_cnt, NN);

    // ---- round 2: read QA (all), write QB ----
    {
        if (t < NK / 4) ((f4_t*)sQ)[t] = ((const f4_t*)QA)[t];
        __syncthreads();
        const f4_t* q4 = (const f4_t*)sQ;
        float acc = 0.f;
        #pragma unroll
        for (int j = 0; j < 5; ++j) {
            f4_t r = row[lane + 64 * j];
            f4_t q = q4[lane + 64 * j];
            acc += r.x * q.x + r.y * q.y + r.z * q.z + r.w * q.w;
        }
        #pragma unroll
        for (int m = 32; m > 0; m >>= 1) acc += __shfl_xor(acc, m, 64);
        if (lane == 0) smsg[wave] = acc;
        __syncthreads();
        if (t == 0) {
            float e[KK], mx = -1e30f;
            #pragma unroll
            for (int k = 0; k < KK; ++k) {
                float v = W_BIN_C * smsg[k] + un[k];
                e[k] = v;
                if (v > mx) mx = v;
            }
            float ssum = 0.f;
            #pragma unroll
            for (int k = 0; k < KK; ++k) { e[k] = expf(e[k] - mx); ssum += e[k]; }
            #pragma unroll
            for (int k = 0; k < KK; ++k) QB[a * KK + k] = e[k] / ssum;
        }
    }
    grid_barrier(sync_cnt, 2 * NN);

    // ---- round 3 + output scatter/mix ----
    {
        if (t < NK / 4) ((f4_t*)sQ)[t] = ((const f4_t*)QB)[t];
        __syncthreads();
        const f4_t* q4 = (const f4_t*)sQ;
        float acc = 0.f;
        #pragma unroll
        for (int j = 0; j < 5; ++j) {
            f4_t r = row[lane + 64 * j];
            f4_t q = q4[lane + 64 * j];
            acc += r.x * q.x + r.y * q.y + r.z * q.z + r.w * q.w;
        }
        #pragma unroll
        for (int m = 32; m > 0; m >>= 1) acc += __shfl_xor(acc, m, 64);
        if (lane == 0) smsg[wave] = acc;
        __syncthreads();
        if (t == 0) {
            float e[KK], mx = -1e30f;
            #pragma unroll
            for (int k = 0; k < KK; ++k) {
                float v = W_BIN_C * smsg[k] + un[k];
                e[k] = v;
                if (v > mx) mx = v;
            }
            float ssum = 0.f;
            #pragma unroll
            for (int k = 0; k < KK; ++k) { e[k] = expf(e[k] - mx); ssum += e[k]; }
            #pragma unroll
            for (int k = 0; k < KK; ++k) sq[k] = e[k] / ssum;
        }
        __syncthreads();
        for (int c = t; c < CC; c += 640) {
            float q = 0.f;
            #pragma unroll
            for (int k = 0; k < KK; ++k) if (sL[k] == c) q = sq[k];
            out[a * CC + c] = (roi[a * CC + c] + MIX_C * q) / (1.0f + MIX_C);
        }
    }
}

extern "C" void kernel_launch(void* const* d_in, const int* in_sizes, int n_in,
                              void* d_out, int out_size, void* d_ws, size_t ws_size,
                              hipStream_t stream) {
    const float* roi    = (const float*)d_in[0];  // (128, 1001)
    const float* rel    = (const float*)d_in[1];  // (16384, 51)
    const float* relmat = (const float*)d_in[2];  // (1001, 1001, 51)
    float* out = (float*)d_out;

    // workspace layout (16B-aligned)
    char* ws = (char*)d_ws;
    float* bt       = (float*)ws;                                   // 6,553,600 B
    int*   labels   = (int*)(ws + (size_t)BT_ELEMS * 4);            // 5,120 B
    float* unary    = (float*)(ws + (size_t)BT_ELEMS * 4 + 5120);   // 5,120 B
    float* QA       = unary + NK;
    float* QB       = QA + NK;
    int*   sync_cnt = (int*)(QB + NK);

    hipMemsetAsync(sync_cnt, 0, sizeof(int), stream);
    topk_kernel<<<NN, 64, 0, stream>>>(roi, labels, unary);
    pair_kernel<<<NN * NN, 256, 0, stream>>>(rel, relmat, labels, bt);
    rounds_kernel<<<NN, 640, 0, stream>>>(bt, unary, QA, QB, roi, labels, out, sync_cnt);
}

// Round 13
// 92.981 us; speedup vs baseline: 1.2701x; 1.0006x over previous
//
#include <hip/hip_runtime.h>
#include <hip/hip_bf16.h>

#define NN 128
#define CC 1001
#define RR 51
#define KK 10
#define NK (NN*KK)              // 1280
#define BT_ELEMS (NN*KK*NN*KK) // 1,638,400
#define W_BIN_C 1.0f
#define MIX_C 10000.0f

typedef float f4_t __attribute__((ext_vector_type(4)));
typedef f4_t f4u __attribute__((aligned(4)));   // 4-byte-aligned float4 load

// ---------------- top-k: one wave per row, all-register ----------------
__global__ __launch_bounds__(64) void topk_kernel(const float* __restrict__ roi,
                                                  int* __restrict__ labels,
                                                  float* __restrict__ unary) {
    int a = blockIdx.x, lane = threadIdx.x;
    const float* rowp = roi + a * CC;
    float v[16];
    #pragma unroll
    for (int j = 0; j < 16; ++j) {
        int c = lane + 64 * j;
        v[j] = (c < CC) ? rowp[c] : -1e30f;
    }
    for (int k = 0; k < KK; ++k) {
        float bv = v[0]; int bj = 0;
        #pragma unroll
        for (int j = 1; j < 16; ++j) if (v[j] > bv) { bv = v[j]; bj = j; }  // ascending: lowest j on tie
        int bc = lane + 64 * bj;
        #pragma unroll
        for (int m = 32; m > 0; m >>= 1) {
            float v2 = __shfl_xor(bv, m, 64);
            int   c2 = __shfl_xor(bc, m, 64);
            if (v2 > bv || (v2 == bv && c2 < bc)) { bv = v2; bc = c2; }
        }
        if (lane == (bc & 63)) {
            int j = bc >> 6;
            #pragma unroll
            for (int jj = 0; jj < 16; ++jj) if (jj == j) v[jj] = -1e30f;  // static index clear
        }
        if (lane == 0) {
            labels[a * KK + k] = bc;
            unary[a * KK + k]  = logf(bv);
        }
    }
}

// ---------------- fused raw + symmetrize + log ----------------
// XCD-swizzled block mapping: xcd = orig&7, idx = orig>>3,
// a = (idx>>7)*8 + xcd, b = idx&127. Under round-robin block->XCD dispatch,
// XCD c processes a = c, 8+c, ... sequentially, each a's full b-sweep staying
// on that XCD -> the ~3MB used-row set of relmat[La_k,*]/[*,La_k] is
// L2-resident across the sweep. [R10: 95 -> 79.8 us total]
__global__ __launch_bounds__(256) void pair_kernel(const float* __restrict__ rel_scores,
                                                   const float* __restrict__ relmat,
                                                   const int* __restrict__ labels,
                                                   float* __restrict__ bt) {
    int orig = blockIdx.x;
    int xcd = orig & 7;
    int idx = orig >> 3;
    int a = (idx >> 7) * 8 + xcd;
    int b = idx & 127;
    if (a > b) return;
    int t = threadIdx.x;
    if (a == b) {
        if (t < 100) {
            int k = t / 10, l = t % 10;
            bt[((a * KK + k) * NN + a) * KK + l] = 0.0f;
        }
        return;
    }

    __shared__ int   La[KK], Lb[KK];
    __shared__ int   baseAB[100], baseBA[100], oAB[100], oBA[100];
    __shared__ float eAB[RR], eBA[RR];

    if (t < KK)            La[t]      = labels[a * KK + t];
    else if (t < 2 * KK)   Lb[t - KK] = labels[b * KK + (t - KK)];
    if (t >= 64  && t < 64 + RR)  eAB[t - 64]  = expf(rel_scores[(a * NN + b) * RR + (t - 64)]);
    if (t >= 128 && t < 128 + RR) eBA[t - 128] = expf(rel_scores[(b * NN + a) * RR + (t - 128)]);
    __syncthreads();
    if (t < 100) {
        int k = t / 10, l = t % 10;
        baseAB[t] = (La[k] * CC + Lb[l]) * RR;
        baseBA[t] = (Lb[l] * CC + La[k]) * RR;
        oAB[t]    = ((a * KK + k) * NN + b) * KK + l;
        oBA[t]    = ((b * KK + l) * NN + a) * KK + k;
    }
    __syncthreads();

    int gid = t >> 3;      // 0..31
    int sub = t & 7;
    bool act0 = sub < 7, act1 = sub < 6;
    int r0 = (sub < 6) ? sub * 8 : 47;   // lane 6: r=47..50, x zeroed (47 counted by lane 5)
    int r1 = sub * 8 + 4;

    f4_t zero; zero.x = zero.y = zero.z = zero.w = 0.f;
    f4_t c0A = zero, c1A = zero, c0B = zero, c1B = zero;
    if (sub < 6) {
        c0A.x = eAB[r0];   c0A.y = eAB[r0+1]; c0A.z = eAB[r0+2]; c0A.w = eAB[r0+3];
        c1A.x = eAB[r1];   c1A.y = eAB[r1+1]; c1A.z = eAB[r1+2]; c1A.w = eAB[r1+3];
        c0B.x = eBA[r0];   c0B.y = eBA[r0+1]; c0B.z = eBA[r0+2]; c0B.w = eBA[r0+3];
        c1B.x = eBA[r1];   c1B.y = eBA[r1+1]; c1B.z = eBA[r1+2]; c1B.w = eBA[r1+3];
    } else if (sub == 6) {
        c0A.x = 0.f; c0A.y = eAB[48]; c0A.z = eAB[49]; c0A.w = eAB[50];
        c0B.x = 0.f; c0B.y = eBA[48]; c0B.z = eBA[49]; c0B.w = eBA[50];
    }

    f4_t A0[4], A1[4], B0[4], B1[4];
    #pragma unroll
    for (int u = 0; u < 4; ++u) {
        int kl = gid + 32 * u;
        bool h = (kl < 100);
        int kls = h ? kl : 0;
        int bA = baseAB[kls], bB = baseBA[kls];
        A0[u] = (h && act0) ? *(const f4u*)(relmat + bA + r0) : zero;
        A1[u] = (h && act1) ? *(const f4u*)(relmat + bA + r1) : zero;
        B0[u] = (h && act0) ? *(const f4u*)(relmat + bB + r0) : zero;
        B1[u] = (h && act1) ? *(const f4u*)(relmat + bB + r1) : zero;
    }
    float s[4];
    #pragma unroll
    for (int u = 0; u < 4; ++u) {
        s[u] = A0[u].x*c0A.x + A0[u].y*c0A.y + A0[u].z*c0A.z + A0[u].w*c0A.w
             + A1[u].x*c1A.x + A1[u].y*c1A.y + A1[u].z*c1A.z + A1[u].w*c1A.w
             + B0[u].x*c0B.x + B0[u].y*c0B.y + B0[u].z*c0B.z + B0[u].w*c0B.w
             + B1[u].x*c1B.x + B1[u].y*c1B.y + B1[u].z*c1B.z + B1[u].w*c1B.w;
    }
    #pragma unroll
    for (int m = 4; m > 0; m >>= 1) {
        #pragma unroll
        for (int u = 0; u < 4; ++u) s[u] += __shfl_xor(s[u], m, 64);
    }
    if (sub == 0) {
        #pragma unroll
        for (int u = 0; u < 4; ++u) {
            int kl = gid + 32 * u;
            if (kl < 100) {
                float vv = logf(0.5f * s[u]);
                bt[oAB[kl]] = vv;
                bt[oBA[kl]] = vv;
            }
        }
    }
}

// ---------------- manual grid barrier, relaxed polling ----------------
// Arrive: RELEASE fetch_add (one wbl2). Spin: RELAXED agent-scope atomic
// loads — bypass L1/L2 for coherence (observe remote XCD updates) WITHOUT
// emitting invalidates, so bt stays L2-hot. Exit: single ACQUIRE fence.
__device__ inline void grid_barrier(int* cnt, int target) {
    __syncthreads();
    if (threadIdx.x == 0) {
        __hip_atomic_fetch_add(cnt, 1, __ATOMIC_RELEASE, __HIP_MEMORY_SCOPE_AGENT);
        while (__hip_atomic_load(cnt, __ATOMIC_RELAXED, __HIP_MEMORY_SCOPE_AGENT) < target) {
            __builtin_amdgcn_s_sleep(2);
        }
        __builtin_amdgcn_fence(__ATOMIC_ACQUIRE, "agent");
    }
    __syncthreads();
}

// ---------------- all 3 mean-field rounds + output, one normal launch ----------------
// 128 blocks x 640 threads (10 waves; wave k owns bt row (a,k)); 1 block/CU
// so all blocks trivially co-resident.
__global__ __launch_bounds__(640) void rounds_kernel(const float* __restrict__ bt,
                                                     const float* __restrict__ unary,
                                                     float* __restrict__ QA,
                                                     float* __restrict__ QB,
                                                     const float* __restrict__ roi,
                                                     const int* __restrict__ labels,
                                                     float* __restrict__ out,
                                                     int* __restrict__ sync_cnt) {
    int a = blockIdx.x, t = threadIdx.x;
    int wave = t >> 6, lane = t & 63;
    __shared__ float sQ[NK];
    __shared__ float smsg[KK];
    __shared__ float sq[KK];
    __shared__ int   sL[KK];

    const f4_t* row = (const f4_t*)(bt + (a * KK + wave) * NK);
    float un[KK];   // only used by t==0
    if (t == 0) {
        #pragma unroll
        for (int k = 0; k < KK; ++k) un[k] = unary[a * KK + k];
    }
    if (t >= 320 && t < 320 + KK) sL[t - 320] = labels[a * KK + (t - 320)];

    // ---- round 1: uniform Q = 1/K  ->  msg = rowsum/K ----
    {
        float acc = 0.f;
        #pragma unroll
        for (int j = 0; j < 5; ++j) {
            f4_t r = row[lane + 64 * j];
            acc += r.x + r.y + r.z + r.w;
        }
        acc *= (1.0f / (float)KK);
        #pragma unroll
        for (int m = 32; m > 0; m >>= 1) acc += __shfl_xor(acc, m, 64);
        if (lane == 0) smsg[wave] = acc;
        __syncthreads();
        if (t == 0) {
            float e[KK], mx = -1e30f;
            #pragma unroll
            for (int k = 0; k < KK; ++k) {
                float v = W_BIN_C * smsg[k] + un[k];
                e[k] = v;
                if (v > mx) mx = v;
            }
            float ssum = 0.f;
            #pragma unroll
            for (int k = 0; k < KK; ++k) { e[k] = expf(e[k] - mx); ssum += e[k]; }
            #pragma unroll
            for (int k = 0; k < KK; ++k) QA[a * KK + k] = e[k] / ssum;
        }
    }
    grid_barrier(sync_cnt, NN);

    // ---- round 2: read QA (all), write QB ----
    {
        if (t < NK / 4) ((f4_t*)sQ)[t] = ((const f4_t*)QA)[t];
        __syncthreads();
        const f4_t* q4 = (const f4_t*)sQ;
        float acc = 0.f;
        #pragma unroll
        for (int j = 0; j < 5; ++j) {
            f4_t r = row[lane + 64 * j];
            f4_t q = q4[lane + 64 * j];
            acc += r.x * q.x + r.y * q.y + r.z * q.z + r.w * q.w;
        }
        #pragma unroll
        for (int m = 32; m > 0; m >>= 1) acc += __shfl_xor(acc, m, 64);
        if (lane == 0) smsg[wave] = acc;
        __syncthreads();
        if (t == 0) {
            float e[KK], mx = -1e30f;
            #pragma unroll
            for (int k = 0; k < KK; ++k) {
                float v = W_BIN_C * smsg[k] + un[k];
                e[k] = v;
                if (v > mx) mx = v;
            }
            float ssum = 0.f;
            #pragma unroll
            for (int k = 0; k < KK; ++k) { e[k] = expf(e[k] - mx); ssum += e[k]; }
            #pragma unroll
            for (int k = 0; k < KK; ++k) QB[a * KK + k] = e[k] / ssum;
        }
    }
    grid_barrier(sync_cnt, 2 * NN);

    // ---- round 3 + output scatter/mix ----
    {
        if (t < NK / 4) ((f4_t*)sQ)[t] = ((const f4_t*)QB)[t];
        __syncthreads();
        const f4_t* q4 = (const f4_t*)sQ;
        float acc = 0.f;
        #pragma unroll
        for (int j = 0; j < 5; ++j) {
            f4_t r = row[lane + 64 * j];
            f4_t q = q4[lane + 64 * j];
            acc += r.x * q.x + r.y * q.y + r.z * q.z + r.w * q.w;
        }
        #pragma unroll
        for (int m = 32; m > 0; m >>= 1) acc += __shfl_xor(acc, m, 64);
        if (lane == 0) smsg[wave] = acc;
        __syncthreads();
        if (t == 0) {
            float e[KK], mx = -1e30f;
            #pragma unroll
            for (int k = 0; k < KK; ++k) {
                float v = W_BIN_C * smsg[k] + un[k];
                e[k] = v;
                if (v > mx) mx = v;
            }
            float ssum = 0.f;
            #pragma unroll
            for (int k = 0; k < KK; ++k) { e[k] = expf(e[k] - mx); ssum += e[k]; }
            #pragma unroll
            for (int k = 0; k < KK; ++k) sq[k] = e[k] / ssum;
        }
        __syncthreads();
        for (int c = t; c < CC; c += 640) {
            float q = 0.f;
            #pragma unroll
            for (int k = 0; k < KK; ++k) if (sL[k] == c) q = sq[k];
            out[a * CC + c] = (roi[a * CC + c] + MIX_C * q) / (1.0f + MIX_C);
        }
    }
}

extern "C" void kernel_launch(void* const* d_in, const int* in_sizes, int n_in,
                              void* d_out, int out_size, void* d_ws, size_t ws_size,
                              hipStream_t stream) {
    const float* roi    = (const float*)d_in[0];  // (128, 1001)
    const float* rel    = (const float*)d_in[1];  // (16384, 51)
    const float* relmat = (const float*)d_in[2];  // (1001, 1001, 51)
    float* out = (float*)d_out;

    // workspace layout (16B-aligned)
    char* ws = (char*)d_ws;
    float* bt       = (float*)ws;                                   // 6,553,600 B
    int*   labels   = (int*)(ws + (size_t)BT_ELEMS * 4);            // 5,120 B
    float* unary    = (float*)(ws + (size_t)BT_ELEMS * 4 + 5120);   // 5,120 B
    float* QA       = unary + NK;
    float* QB       = QA + NK;
    int*   sync_cnt = (int*)(QB + NK);

    hipMemsetAsync(sync_cnt, 0, sizeof(int), stream);
    topk_kernel<<<NN, 64, 0, stream>>>(roi, labels, unary);
    pair_kernel<<<NN * NN, 256, 0, stream>>>(rel, relmat, labels, bt);
    rounds_kernel<<<NN, 640, 0, stream>>>(bt, unary, QA, QB, roi, labels, out, sync_cnt);
}

// Round 14
// 79.834 us; speedup vs baseline: 1.4793x; 1.1647x over previous
//
#include <hip/hip_runtime.h>
#include <hip/hip_bf16.h>

#define NN 128
#define CC 1001
#define RR 51
#define KK 10
#define NK (NN*KK)              // 1280
#define BT_ELEMS (NN*KK*NN*KK) // 1,638,400
#define W_BIN_C 1.0f
#define MIX_C 10000.0f

typedef float f4_t __attribute__((ext_vector_type(4)));
typedef f4_t f4u __attribute__((aligned(4)));   // 4-byte-aligned float4 load

// ---------------- top-k: one wave per row, all-register ----------------
__global__ __launch_bounds__(64) void topk_kernel(const float* __restrict__ roi,
                                                  int* __restrict__ labels,
                                                  float* __restrict__ unary) {
    int a = blockIdx.x, lane = threadIdx.x;
    const float* rowp = roi + a * CC;
    float v[16];
    #pragma unroll
    for (int j = 0; j < 16; ++j) {
        int c = lane + 64 * j;
        v[j] = (c < CC) ? rowp[c] : -1e30f;
    }
    for (int k = 0; k < KK; ++k) {
        float bv = v[0]; int bj = 0;
        #pragma unroll
        for (int j = 1; j < 16; ++j) if (v[j] > bv) { bv = v[j]; bj = j; }  // ascending: lowest j on tie
        int bc = lane + 64 * bj;
        #pragma unroll
        for (int m = 32; m > 0; m >>= 1) {
            float v2 = __shfl_xor(bv, m, 64);
            int   c2 = __shfl_xor(bc, m, 64);
            if (v2 > bv || (v2 == bv && c2 < bc)) { bv = v2; bc = c2; }
        }
        if (lane == (bc & 63)) {
            int j = bc >> 6;
            #pragma unroll
            for (int jj = 0; jj < 16; ++jj) if (jj == j) v[jj] = -1e30f;  // static index clear
        }
        if (lane == 0) {
            labels[a * KK + k] = bc;
            unary[a * KK + k]  = logf(bv);
        }
    }
}

// ---------------- fused raw + symmetrize + log ----------------
// XCD-swizzled block mapping: xcd = orig&7, idx = orig>>3,
// a = (idx>>7)*8 + xcd, b = idx&127. Under round-robin block->XCD dispatch,
// XCD c processes a = c, 8+c, ... sequentially, each a's full b-sweep staying
// on that XCD -> the ~3MB used-row set of relmat[La_k,*]/[*,La_k] is
// L2-resident across the sweep. [R10: 95 -> 79.8 us total]
// 8-lane group per (k,l): lanes 0..5 two f4 (r0..47), lane 6 f4 at r=47 with
// x-coeff zeroed; both directional dots summed before one 3-step reduce.
__global__ __launch_bounds__(256) void pair_kernel(const float* __restrict__ rel_scores,
                                                   const float* __restrict__ relmat,
                                                   const int* __restrict__ labels,
                                                   float* __restrict__ bt) {
    int orig = blockIdx.x;
    int xcd = orig & 7;
    int idx = orig >> 3;
    int a = (idx >> 7) * 8 + xcd;
    int b = idx & 127;
    if (a > b) return;
    int t = threadIdx.x;
    if (a == b) {
        if (t < 100) {
            int k = t / 10, l = t % 10;
            bt[((a * KK + k) * NN + a) * KK + l] = 0.0f;
        }
        return;
    }

    __shared__ int   La[KK], Lb[KK];
    __shared__ int   baseAB[100], baseBA[100], oAB[100], oBA[100];
    __shared__ float eAB[RR], eBA[RR];

    if (t < KK)            La[t]      = labels[a * KK + t];
    else if (t < 2 * KK)   Lb[t - KK] = labels[b * KK + (t - KK)];
    if (t >= 64  && t < 64 + RR)  eAB[t - 64]  = expf(rel_scores[(a * NN + b) * RR + (t - 64)]);
    if (t >= 128 && t < 128 + RR) eBA[t - 128] = expf(rel_scores[(b * NN + a) * RR + (t - 128)]);
    __syncthreads();
    if (t < 100) {
        int k = t / 10, l = t % 10;
        baseAB[t] = (La[k] * CC + Lb[l]) * RR;
        baseBA[t] = (Lb[l] * CC + La[k]) * RR;
        oAB[t]    = ((a * KK + k) * NN + b) * KK + l;
        oBA[t]    = ((b * KK + l) * NN + a) * KK + k;
    }
    __syncthreads();

    int gid = t >> 3;      // 0..31
    int sub = t & 7;
    bool act0 = sub < 7, act1 = sub < 6;
    int r0 = (sub < 6) ? sub * 8 : 47;   // lane 6: r=47..50, x zeroed (47 counted by lane 5)
    int r1 = sub * 8 + 4;

    f4_t zero; zero.x = zero.y = zero.z = zero.w = 0.f;
    f4_t c0A = zero, c1A = zero, c0B = zero, c1B = zero;
    if (sub < 6) {
        c0A.x = eAB[r0];   c0A.y = eAB[r0+1]; c0A.z = eAB[r0+2]; c0A.w = eAB[r0+3];
        c1A.x = eAB[r1];   c1A.y = eAB[r1+1]; c1A.z = eAB[r1+2]; c1A.w = eAB[r1+3];
        c0B.x = eBA[r0];   c0B.y = eBA[r0+1]; c0B.z = eBA[r0+2]; c0B.w = eBA[r0+3];
        c1B.x = eBA[r1];   c1B.y = eBA[r1+1]; c1B.z = eBA[r1+2]; c1B.w = eBA[r1+3];
    } else if (sub == 6) {
        c0A.x = 0.f; c0A.y = eAB[48]; c0A.z = eAB[49]; c0A.w = eAB[50];
        c0B.x = 0.f; c0B.y = eBA[48]; c0B.z = eBA[49]; c0B.w = eBA[50];
    }

    f4_t A0[4], A1[4], B0[4], B1[4];
    #pragma unroll
    for (int u = 0; u < 4; ++u) {
        int kl = gid + 32 * u;
        bool h = (kl < 100);
        int kls = h ? kl : 0;
        int bA = baseAB[kls], bB = baseBA[kls];
        A0[u] = (h && act0) ? *(const f4u*)(relmat + bA + r0) : zero;
        A1[u] = (h && act1) ? *(const f4u*)(relmat + bA + r1) : zero;
        B0[u] = (h && act0) ? *(const f4u*)(relmat + bB + r0) : zero;
        B1[u] = (h && act1) ? *(const f4u*)(relmat + bB + r1) : zero;
    }
    float s[4];
    #pragma unroll
    for (int u = 0; u < 4; ++u) {
        s[u] = A0[u].x*c0A.x + A0[u].y*c0A.y + A0[u].z*c0A.z + A0[u].w*c0A.w
             + A1[u].x*c1A.x + A1[u].y*c1A.y + A1[u].z*c1A.z + A1[u].w*c1A.w
             + B0[u].x*c0B.x + B0[u].y*c0B.y + B0[u].z*c0B.z + B0[u].w*c0B.w
             + B1[u].x*c1B.x + B1[u].y*c1B.y + B1[u].z*c1B.z + B1[u].w*c1B.w;
    }
    #pragma unroll
    for (int m = 4; m > 0; m >>= 1) {
        #pragma unroll
        for (int u = 0; u < 4; ++u) s[u] += __shfl_xor(s[u], m, 64);
    }
    if (sub == 0) {
        #pragma unroll
        for (int u = 0; u < 4; ++u) {
            int kl = gid + 32 * u;
            if (kl < 100) {
                float vv = logf(0.5f * s[u]);
                bt[oAB[kl]] = vv;
                bt[oBA[kl]] = vv;
            }
        }
    }
}

// ---------------- mean-field round: 10 waves, wave k owns row k ----------------
__global__ __launch_bounds__(640) void round_kernel(const float* __restrict__ bt,
                                                    const float* __restrict__ unary,
                                                    const float* __restrict__ Qin,
                                                    float* __restrict__ Qout,
                                                    int uniform) {
    int a = blockIdx.x, t = threadIdx.x;
    int wave = t >> 6, lane = t & 63;
    __shared__ float sQ[NK];
    __shared__ float smsg[KK];
    if (!uniform && t < NK / 4) ((f4_t*)sQ)[t] = ((const f4_t*)Qin)[t];
    __syncthreads();
    const f4_t* row = (const f4_t*)(bt + (a * KK + wave) * NK);
    float acc = 0.f;
    if (uniform) {
        #pragma unroll
        for (int j = 0; j < 5; ++j) {
            f4_t r = row[lane + 64 * j];
            acc += r.x + r.y + r.z + r.w;
        }
        acc *= (1.0f / (float)KK);
    } else {
        const f4_t* q4 = (const f4_t*)sQ;
        #pragma unroll
        for (int j = 0; j < 5; ++j) {
            f4_t r = row[lane + 64 * j];
            f4_t q = q4[lane + 64 * j];
            acc += r.x * q.x + r.y * q.y + r.z * q.z + r.w * q.w;
        }
    }
    #pragma unroll
    for (int m = 32; m > 0; m >>= 1) acc += __shfl_xor(acc, m, 64);
    if (lane == 0) smsg[wave] = acc;
    __syncthreads();
    if (t == 0) {
        float e[KK], m = -1e30f;
        #pragma unroll
        for (int k = 0; k < KK; ++k) {
            float v = W_BIN_C * smsg[k] + unary[a * KK + k];
            e[k] = v;
            if (v > m) m = v;
        }
        float s = 0.f;
        #pragma unroll
        for (int k = 0; k < KK; ++k) { e[k] = expf(e[k] - m); s += e[k]; }
        #pragma unroll
        for (int k = 0; k < KK; ++k) Qout[a * KK + k] = e[k] / s;
    }
}

// ---------------- final round fused with output scatter/mix ----------------
__global__ __launch_bounds__(640) void round_out_kernel(const float* __restrict__ bt,
                                                        const float* __restrict__ unary,
                                                        const float* __restrict__ Qin,
                                                        const float* __restrict__ roi,
                                                        const int* __restrict__ labels,
                                                        float* __restrict__ out) {
    int a = blockIdx.x, t = threadIdx.x;
    int wave = t >> 6, lane = t & 63;
    __shared__ float sQ[NK];
    __shared__ float smsg[KK];
    __shared__ float sq[KK];
    __shared__ int   sL[KK];
    if (t < NK / 4) ((f4_t*)sQ)[t] = ((const f4_t*)Qin)[t];
    if (t >= 320 && t < 320 + KK) sL[t - 320] = labels[a * KK + (t - 320)];
    __syncthreads();
    const f4_t* row = (const f4_t*)(bt + (a * KK + wave) * NK);
    const f4_t* q4  = (const f4_t*)sQ;
    float acc = 0.f;
    #pragma unroll
    for (int j = 0; j < 5; ++j) {
        f4_t r = row[lane + 64 * j];
        f4_t q = q4[lane + 64 * j];
        acc += r.x * q.x + r.y * q.y + r.z * q.z + r.w * q.w;
    }
    #pragma unroll
    for (int m = 32; m > 0; m >>= 1) acc += __shfl_xor(acc, m, 64);
    if (lane == 0) smsg[wave] = acc;
    __syncthreads();
    if (t == 0) {
        float e[KK], m = -1e30f;
        #pragma unroll
        for (int k = 0; k < KK; ++k) {
            float v = W_BIN_C * smsg[k] + unary[a * KK + k];
            e[k] = v;
            if (v > m) m = v;
        }
        float s = 0.f;
        #pragma unroll
        for (int k = 0; k < KK; ++k) { e[k] = expf(e[k] - m); s += e[k]; }
        #pragma unroll
        for (int k = 0; k < KK; ++k) sq[k] = e[k] / s;
    }
    __syncthreads();
    for (int c = t; c < CC; c += 640) {
        float q = 0.f;
        #pragma unroll
        for (int k = 0; k < KK; ++k) if (sL[k] == c) q = sq[k];
        out[a * CC + c] = (roi[a * CC + c] + MIX_C * q) / (1.0f + MIX_C);
    }
}

extern "C" void kernel_launch(void* const* d_in, const int* in_sizes, int n_in,
                              void* d_out, int out_size, void* d_ws, size_t ws_size,
                              hipStream_t stream) {
    const float* roi    = (const float*)d_in[0];  // (128, 1001)
    const float* rel    = (const float*)d_in[1];  // (16384, 51)
    const float* relmat = (const float*)d_in[2];  // (1001, 1001, 51)
    float* out = (float*)d_out;

    // workspace layout (16B-aligned)
    char* ws = (char*)d_ws;
    float* bt     = (float*)ws;                                   // 6,553,600 B
    int*   labels = (int*)(ws + (size_t)BT_ELEMS * 4);            // 5,120 B
    float* unary  = (float*)(ws + (size_t)BT_ELEMS * 4 + 5120);   // 5,120 B
    float* QA     = unary + NK;
    float* QB     = QA + NK;

    topk_kernel<<<NN, 64, 0, stream>>>(roi, labels, unary);
    pair_kernel<<<NN * NN, 256, 0, stream>>>(rel, relmat, labels, bt);
    round_kernel<<<NN, 640, 0, stream>>>(bt, unary, QA, QA, 1);       // round 1: uniform Q
    round_kernel<<<NN, 640, 0, stream>>>(bt, unary, QA, QB, 0);       // round 2
    round_out_kernel<<<NN, 640, 0, stream>>>(bt, unary, QB, roi, labels, out);  // round 3 + mix
}